// Round 10
// baseline (965.886 us; speedup 1.0000x reference)
//
#include <hip/hip_runtime.h>
#include <math.h>

#define NSWEEP 9
#define NIT2   ((NSWEEP * 63 + 1) / 2)   // 284 double-rounds = 568 rounds

// ws layout (float offsets)
#define WS_T16 0            // 32*128 f16 = 2048 floats
#define WS_IU  2048
#define WS_JU  4128
#define WS_MU  6208
#define WS_SC  8288
#define WS_ACC 10368
#define WS_COV 16384                     // 320*4096 floats
#define WS_VEC (16384 + 320*4096)        // 320*2080 floats
#define WS_Z   1994752                   // f16 Z buffer starts here (floats)

typedef _Float16 f16x8 __attribute__((ext_vector_type(8)));
typedef float f32x16 __attribute__((ext_vector_type(16)));

union H8 { int4 i; f16x8 h; };
union HP { uint32_t u; _Float16 h[2]; };

__device__ inline f32x16 zero16() {
    f32x16 z;
#pragma unroll
    for (int r = 0; r < 16; r++) z[r] = 0.0f;
    return z;
}

__device__ __forceinline__ float bperm(int addr, float v) {
    return __int_as_float(__builtin_amdgcn_ds_bpermute(addr, __float_as_int(v)));
}

// ---------------------------------------------------------------------------
// K0: wavelet taps as fp16 matrix T16[32][128] + triu tables
// ---------------------------------------------------------------------------
__global__ void k0_build(const float* __restrict__ foi, const float* __restrict__ fwhm,
                         _Float16* __restrict__ T16,
                         int* __restrict__ iu, int* __restrict__ ju) {
    __shared__ float env[128];
    __shared__ float ssum;
    int tid = threadIdx.x;
    for (int u = tid; u < 2080; u += 256) {
        int i = 0, off = 0;
        while (off + (64 - i) <= u) { off += (64 - i); i++; }
        iu[u] = i;
        ju[u] = i + (u - off);
    }
    for (int idx = tid; idx < 32 * 128; idx += 256) T16[idx] = (_Float16)0.0f;
    __syncthreads();
    const float inv_sfreq = 1.0f / 250.0f;
    for (int f = 0; f < 10; f++) {
        float fhz = exp2f(foi[f]);
        float sig = exp2f(fwhm[f]) / (2.0f * sqrtf(2.0f * logf(2.0f)));
        if (tid < 128) {
            float e = 0.0f;
            if (tid < 125) {
                float t = ((float)tid - 62.0f) * inv_sfreq;
                float z = t / sig;
                e = expf(-0.5f * z * z);
            }
            env[tid] = e;
        }
        __syncthreads();
        if (tid == 0) {
            float s = 0.0f;
            for (int k = 0; k < 125; k++) s += env[k];
            ssum = s;
        }
        __syncthreads();
        if (tid < 125) {
            float e = env[tid] / ssum;
            float t = ((float)tid - 62.0f) * inv_sfreq;
            float ph = 6.283185307179586f * fhz * t;
            T16[f * 128 + tid] = (_Float16)(e * cosf(ph));
            T16[(10 + f) * 128 + tid] = (_Float16)(e * sinf(ph));
        }
        __syncthreads();
    }
}

// ---------------------------------------------------------------------------
// KCONV: fp16 MFMA conv (unchanged)
// ---------------------------------------------------------------------------
__global__ __launch_bounds__(256) void kconv(const float* __restrict__ X,
                                             const _Float16* __restrict__ T16,
                                             _Float16* __restrict__ Zbuf,
                                             int t0chunk, int Tpad, int subs) {
    __shared__ __align__(16) uint32_t P[64 * 256];
    int tid = threadIdx.x;
    int b = blockIdx.x / subs;
    int sub = blockIdx.x - b * subs;
    int tbase = t0chunk + sub * 128;
    const float* Xb = X + b * (64 * 2500);
    bool fastblk = (tbase + 256 < 2500);
    for (int task = tid; task < 64 * 64; task += 256) {
        int c = task >> 6, grp = task & 63;
        int t = tbase + grp * 4;
        const float* src = Xb + c * 2500 + t;
        float x0, x1, x2, x3, x4;
        if (fastblk) {
            float4 v = *(const float4*)src;
            x0 = v.x; x1 = v.y; x2 = v.z; x3 = v.w; x4 = src[4];
        } else {
            x0 = (t + 0 < 2500) ? src[0] : 0.0f;
            x1 = (t + 1 < 2500) ? src[1] : 0.0f;
            x2 = (t + 2 < 2500) ? src[2] : 0.0f;
            x3 = (t + 3 < 2500) ? src[3] : 0.0f;
            x4 = (t + 4 < 2500) ? src[4] : 0.0f;
        }
        HP p0, p1, p2, p3;
        p0.h[0] = (_Float16)x0; p0.h[1] = (_Float16)x1;
        p1.h[0] = (_Float16)x1; p1.h[1] = (_Float16)x2;
        p2.h[0] = (_Float16)x2; p2.h[1] = (_Float16)x3;
        p3.h[0] = (_Float16)x3; p3.h[1] = (_Float16)x4;
        uint4 up; up.x = p0.u; up.y = p1.u; up.z = p2.u; up.w = p3.u;
        *(uint4*)&P[c * 256 + grp * 4] = up;
    }
    __syncthreads();
    int lane = tid & 63;
    int w = tid >> 6;
    int n = lane & 31, g = lane >> 5;
    H8 a[8];
#pragma unroll
    for (int ks = 0; ks < 8; ks++)
        a[ks].i = *(const int4*)(T16 + n * 128 + ks * 16 + g * 8);
    int tw = w * 32;
    int colg = tbase + tw + n;
    bool colok = (colg < 2376);
    int tloc = sub * 128 + tw + n;
    int zb0 = b * 1280;
    for (int c = 0; c < 64; c++) {
        f32x16 acc = zero16();
        const uint32_t* Pc = &P[c * 256 + tw + n + 8 * g];
#pragma unroll
        for (int ks = 0; ks < 8; ks++) {
            H8 bv;
            bv.i.x = (int)Pc[16 * ks + 0];
            bv.i.y = (int)Pc[16 * ks + 2];
            bv.i.z = (int)Pc[16 * ks + 4];
            bv.i.w = (int)Pc[16 * ks + 6];
            acc = __builtin_amdgcn_mfma_f32_32x32x16_f16(a[ks].h, bv.h, acc, 0, 0, 0);
        }
        if (colok) {
            int zb = zb0 + c;
#pragma unroll
            for (int r = 0; r < 16; r++) {
                int row = (r & 3) + 8 * (r >> 2) + 4 * g;
                if (row < 20)
                    Zbuf[(zb + row * 64) * Tpad + tloc] = (_Float16)acc[r];
            }
        }
    }
}

// ---------------------------------------------------------------------------
// KCOV: per (b,f) covariance via MFMA (unchanged)
// ---------------------------------------------------------------------------
__global__ __launch_bounds__(256) void kcov(const _Float16* __restrict__ Zbuf,
                                            float* __restrict__ cov,
                                            int t0chunk, int Tcur, int Tpad) {
    __shared__ __align__(16) _Float16 Zs[2][64 * 100];
    int tid = threadIdx.x;
    int lane = tid & 63, w = tid >> 6;
    int n = lane & 31, g = lane >> 5;
    int bf = blockIdx.x;
    int b = bf / 10, f = bf - b * 10;
    const _Float16* Zr = Zbuf + (size_t)((b * 20 + f) * 64) * Tpad;
    const _Float16* Zi = Zbuf + (size_t)((b * 20 + 10 + f) * 64) * Tpad;
    int ti = w >> 1, tj = w & 1;
    f32x16 acc = zero16();
    int limit = min(Tcur, 2376 - t0chunk);
    int nsub = (limit + 95) / 96;
    for (int sc = 0; sc < nsub; sc++) {
        int tl0 = sc * 96;
        __syncthreads();
        for (int task = tid; task < 1536; task += 256) {
            int arr = task / 768;
            int rem = task - arr * 768;
            int c = rem / 12;
            int o = (rem - c * 12) * 8;
            int tg = tl0 + o;
            const _Float16* src = (arr ? Zi : Zr) + c * Tpad + tg;
            H8 v;
            if (tg + 8 <= limit) {
                v.i = *(const int4*)src;
            } else {
#pragma unroll
                for (int j2 = 0; j2 < 8; j2++)
                    v.h[j2] = (tg + j2 < limit) ? src[j2] : (_Float16)0.0f;
            }
            *(int2*)&Zs[arr][c * 100 + o] = make_int2(v.i.x, v.i.y);
            *(int2*)&Zs[arr][c * 100 + o + 4] = make_int2(v.i.z, v.i.w);
        }
        __syncthreads();
        int ra = (32 * ti + n) * 100 + g * 8;
        int rb = (32 * tj + n) * 100 + g * 8;
#pragma unroll
        for (int arr = 0; arr < 2; arr++) {
#pragma unroll
            for (int ks = 0; ks < 6; ks++) {
                const _Float16* pa = &Zs[arr][ra + ks * 16];
                const _Float16* pb = &Zs[arr][rb + ks * 16];
                int2 a0 = *(const int2*)pa;
                int2 a1 = *(const int2*)(pa + 4);
                int2 b0 = *(const int2*)pb;
                int2 b1 = *(const int2*)(pb + 4);
                H8 av, bv;
                av.i = make_int4(a0.x, a0.y, a1.x, a1.y);
                bv.i = make_int4(b0.x, b0.y, b1.x, b1.y);
                acc = __builtin_amdgcn_mfma_f32_32x32x16_f16(av.h, bv.h, acc, 0, 0, 0);
            }
        }
    }
    float* covbf = cov + bf * 4096;
    int col = 32 * tj + n;
#pragma unroll
    for (int r = 0; r < 16; r++) {
        int row = 32 * ti + (r & 3) + 8 * (r >> 2) + 4 * g;
        covbf[row * 64 + col] += acc[r];
    }
}

// ---------------------------------------------------------------------------
// KEJA6: one-sided Jacobi, one wave per matrix, PING-PONG LDS COLUMN MIRROR.
// r9's 129 ds_bpermute/round (4 B/lane each, ~780 cyc of DS pipe) replaced by
// 48 wide DS ops (16 B/lane): dot pass reads partner column from CUR (16x
// ds_read_b128), update pass re-reads CUR and writes own updated column to
// NXT (16+16). Distinct __shared__ arrays La/Lb let the compiler prove
// read/write disjointness and pipeline all reads (single-array version would
// order-pin every read behind the previous write). Same-wave LDS ops are
// processed in order -> no barriers; NXT becomes CUR next round.
// Quad-XOR swizzle (quad j of column s at s*64 + (j^(s&7))*4): for both own-
// column writes and p=s^m reads, each 8-lane group tiles all 32 banks ->
// conflict-free b128. Rotation uses v_rcp/v_sqrt/v_rsq (rot gate kills NaN).
// ---------------------------------------------------------------------------
__global__ __launch_bounds__(64, 1) void keja6(float* __restrict__ cov,
                                               const float* __restrict__ shrink,
                                               float* __restrict__ dvec,
                                               float* __restrict__ dmu) {
    __shared__ __align__(16) float La[64 * 64];
    __shared__ __align__(16) float Lb[64 * 64];
    int s = threadIdx.x;            // lane = column
    int bf = blockIdx.x;
    float* C = cov + bf * 4096;
    float w[64];
#pragma unroll
    for (int r = 0; r < 64; r++) w[r] = C[r * 64 + s];
    // trace -> mu
    float ts = C[s * 65];
#pragma unroll
    for (int m = 1; m < 64; m <<= 1) ts += __shfl_xor(ts, m, 64);
    float mu = ts * (1.0f / (64.0f * 2376.0f));
    float alpha = 1.0f / (1.0f + expf(-shrink[0]));
    float scl = (1.0f - alpha) / (2376.0f * fmaxf(mu, 1e-30f));
#pragma unroll
    for (int r = 0; r < 64; r++) {
        float v = w[r] * scl;
        if (r == s) v += alpha;
        w[r] = v;
    }
    int sbase = s << 6;
    int sswz = s & 7;
    // initial mirror into La + fresh norm
#pragma unroll
    for (int j = 0; j < 16; j++)
        *(float4*)&La[sbase + ((j ^ sswz) << 2)] =
            make_float4(w[4 * j], w[4 * j + 1], w[4 * j + 2], w[4 * j + 3]);
    float nrm;
    {
        float n0 = 0, n1 = 0, n2 = 0, n3 = 0;
#pragma unroll
        for (int r = 0; r < 64; r += 4) {
            n0 = fmaf(w[r], w[r], n0);
            n1 = fmaf(w[r + 1], w[r + 1], n1);
            n2 = fmaf(w[r + 2], w[r + 2], n2);
            n3 = fmaf(w[r + 3], w[r + 3], n3);
        }
        nrm = (n0 + n1) + (n2 + n3);
    }
    int mA = 1;
#define JROUND(MC, LSRC, LDST)                                                  \
    {                                                                           \
        int p = s ^ (MC);                                                       \
        int pbase = p << 6;                                                     \
        int pswz = p & 7;                                                       \
        float pn = bperm(p << 2, nrm);  /* lands during the dot */              \
        float d0 = 0, d1 = 0, d2 = 0, d3 = 0;                                   \
        _Pragma("unroll")                                                       \
        for (int j = 0; j < 16; j++) {                                          \
            float4 qv = *(const float4*)&LSRC[pbase + ((j ^ pswz) << 2)];       \
            d0 = fmaf(w[4 * j + 0], qv.x, d0);                                  \
            d1 = fmaf(w[4 * j + 1], qv.y, d1);                                  \
            d2 = fmaf(w[4 * j + 2], qv.z, d2);                                  \
            d3 = fmaf(w[4 * j + 3], qv.w, d3);                                  \
        }                                                                       \
        float dpq = (d0 + d1) + (d2 + d3);                                      \
        int h = 31 - __builtin_clz((unsigned)(MC));                             \
        bool top = (((s >> h) & 1) == 0);                                       \
        float dpp = top ? nrm : pn;                                             \
        float dqq = top ? pn : nrm;                                             \
        bool rot = (dpq * dpq > 1e-13f * dpp * dqq);                            \
        float tau = (dqq - dpp) * 0.5f * __builtin_amdgcn_rcpf(dpq);            \
        float tt = __builtin_amdgcn_rcpf(fabsf(tau) +                           \
                    __builtin_amdgcn_sqrtf(fmaf(tau, tau, 1.0f)));              \
        tt = (tau < 0.0f) ? -tt : tt;                                           \
        if (!rot) tt = 0.0f;                                                    \
        float cc = __builtin_amdgcn_rsqf(fmaf(tt, tt, 1.0f));                   \
        float ssn = tt * cc;                                                    \
        float sg = top ? -ssn : ssn;                                            \
        _Pragma("unroll")                                                       \
        for (int j = 0; j < 16; j++) {                                          \
            float4 qv = *(const float4*)&LSRC[pbase + ((j ^ pswz) << 2)];       \
            float w0 = fmaf(cc, w[4 * j + 0], sg * qv.x);                       \
            float w1 = fmaf(cc, w[4 * j + 1], sg * qv.y);                       \
            float w2 = fmaf(cc, w[4 * j + 2], sg * qv.z);                       \
            float w3 = fmaf(cc, w[4 * j + 3], sg * qv.w);                       \
            w[4 * j + 0] = w0; w[4 * j + 1] = w1;                               \
            w[4 * j + 2] = w2; w[4 * j + 3] = w3;                               \
            *(float4*)&LDST[sbase + ((j ^ sswz) << 2)] =                        \
                make_float4(w0, w1, w2, w3);                                    \
        }                                                                       \
        nrm = fmaf(top ? -tt : tt, dpq, nrm);                                   \
    }
#define NORMREFRESH                                                             \
    {                                                                           \
        float n0 = 0, n1 = 0, n2 = 0, n3 = 0;                                   \
        _Pragma("unroll")                                                       \
        for (int r = 0; r < 64; r += 4) {                                       \
            n0 = fmaf(w[r], w[r], n0);                                          \
            n1 = fmaf(w[r + 1], w[r + 1], n1);                                  \
            n2 = fmaf(w[r + 2], w[r + 2], n2);                                  \
            n3 = fmaf(w[r + 3], w[r + 3], n3);                                  \
        }                                                                       \
        nrm = (n0 + n1) + (n2 + n3);                                            \
    }
    for (int it = 0; it < NIT2; it++) {
        int mB = (mA == 63) ? 1 : mA + 1;
        JROUND(mA, La, Lb);
        if (mB == 1) NORMREFRESH;
        int mC = (mB == 63) ? 1 : mB + 1;
        JROUND(mB, Lb, La);
        if (mC == 1) NORMREFRESH;
        mA = mC;
    }
#undef JROUND
#undef NORMREFRESH
    // final exact column norm + output: column s = lambda_s * v_s
    float n0 = 0, n1 = 0, n2 = 0, n3 = 0;
#pragma unroll
    for (int r = 0; r < 64; r += 4) {
        n0 = fmaf(w[r], w[r], n0);
        n1 = fmaf(w[r + 1], w[r + 1], n1);
        n2 = fmaf(w[r + 2], w[r + 2], n2);
        n3 = fmaf(w[r + 3], w[r + 3], n3);
    }
    float nf = (n0 + n1) + (n2 + n3);
#pragma unroll
    for (int r = 0; r < 64; r++) C[r * 64 + s] = w[r];
    dvec[bf * 64 + s] = 0.5f * logf(nf) / nf;   // log(lambda)/lambda^2
    if (s == 0) dmu[bf] = logf(fmaxf(mu, 1e-30f));
}

// ---------------------------------------------------------------------------
// KVEC: logC = sum_s d_s w_s w_s^T ; triu vectorize with sqrt2 / +logmu diag
// ---------------------------------------------------------------------------
__global__ __launch_bounds__(256) void kvec(const float* __restrict__ W,
                                            const float* __restrict__ dvec,
                                            const float* __restrict__ dmu,
                                            const int* __restrict__ iu,
                                            const int* __restrict__ ju,
                                            float* __restrict__ vec) {
    __shared__ float WL[64 * 68];
    __shared__ float WD[64 * 68];
    __shared__ float ds[64];
    int tid = threadIdx.x;
    int bf = blockIdx.x;
    const float* Wb = W + bf * 4096;
    if (tid < 64) ds[tid] = dvec[bf * 64 + tid];
    __syncthreads();
    for (int idx = tid; idx < 4096; idx += 256) {
        int i = idx >> 6, c = idx & 63;
        float v = Wb[idx];
        WL[i * 68 + c] = v;
        WD[i * 68 + c] = v * ds[c];
    }
    __syncthreads();
    float logmu = dmu[bf];
    float* out = vec + bf * 2080;
    for (int u = tid; u < 2080; u += 256) {
        int i = iu[u], j = ju[u];
        const float* a = &WD[i * 68];
        const float* b = &WL[j * 68];
        float s0 = 0, s1 = 0, s2 = 0, s3 = 0;
#pragma unroll
        for (int k = 0; k < 64; k += 16) {
            float4 a0 = *(const float4*)(a + k);
            float4 b0 = *(const float4*)(b + k);
            float4 a1 = *(const float4*)(a + k + 4);
            float4 b1 = *(const float4*)(b + k + 4);
            float4 a2 = *(const float4*)(a + k + 8);
            float4 b2 = *(const float4*)(b + k + 8);
            float4 a3 = *(const float4*)(a + k + 12);
            float4 b3 = *(const float4*)(b + k + 12);
            s0 = fmaf(a0.x, b0.x, fmaf(a0.y, b0.y, fmaf(a0.z, b0.z, fmaf(a0.w, b0.w, s0))));
            s1 = fmaf(a1.x, b1.x, fmaf(a1.y, b1.y, fmaf(a1.z, b1.z, fmaf(a1.w, b1.w, s1))));
            s2 = fmaf(a2.x, b2.x, fmaf(a2.y, b2.y, fmaf(a2.z, b2.z, fmaf(a2.w, b2.w, s2))));
            s3 = fmaf(a3.x, b3.x, fmaf(a3.y, b3.y, fmaf(a3.z, b3.z, fmaf(a3.w, b3.w, s3))));
        }
        float ssm = (s0 + s1) + (s2 + s3);
        if (i == j) ssm += logmu;
        else ssm *= 1.4142135623730951f;
        out[u] = ssm;
    }
}

// ---------------------------------------------------------------------------
__global__ void k3a_stats(const float* __restrict__ vec, const float* __restrict__ brn_w,
                          float* __restrict__ m_u, float* __restrict__ sc_u) {
    int u = blockIdx.x * 256 + threadIdx.x;
    if (u >= 2080) return;
    float s1 = 0.0f, s2 = 0.0f;
    for (int bfi = 0; bfi < 320; bfi++) {
        float x = vec[bfi * 2080 + u];
        s1 += x; s2 += x * x;
    }
    float m = s1 * (1.0f / 320.0f);
    float v = s2 * (1.0f / 320.0f) - m * m;
    m_u[u] = m;
    sc_u[u] = brn_w[u] * rsqrtf(v + 1e-5f);
}

__global__ __launch_bounds__(256) void k3b_bn1mm(const float* __restrict__ vec,
                                                 const float* __restrict__ m_u,
                                                 const float* __restrict__ sc_u,
                                                 const float* __restrict__ g1,
                                                 const float* __restrict__ bb1,
                                                 const float* __restrict__ W1,
                                                 float* __restrict__ acc) {
    __shared__ float hbuf[256 * 33];
    __shared__ float wbuf[8 * 256];
    int tid = threadIdx.x;
    int j = blockIdx.x * 256 + tid;
    bool act = (j < 20800);
    int f = act ? (j / 2080) : 0;
    int u = act ? (j % 2080) : 0;
    float mm = act ? m_u[u] : 0.0f;
    float sc = act ? sc_u[u] : 0.0f;
    float xv[32];
    float s1 = 0.0f, s2 = 0.0f;
    for (int b = 0; b < 32; b++) {
        float x = act ? ((vec[(b * 10 + f) * 2080 + u] - mm) * sc) : 0.0f;
        xv[b] = x;
        s1 += x; s2 += x * x;
    }
    float m1 = s1 * (1.0f / 32.0f);
    float inv1 = rsqrtf(s2 * (1.0f / 32.0f) - m1 * m1 + 1e-5f);
    float gg = act ? g1[j] : 0.0f;
    float bb = act ? bb1[j] : 0.0f;
    for (int b = 0; b < 32; b++)
        hbuf[tid * 33 + b] = (xv[b] - m1) * inv1 * gg + bb;
    for (int hid = 0; hid < 8; hid++)
        wbuf[hid * 256 + tid] = act ? W1[hid * 20800 + j] : 0.0f;
    __syncthreads();
    int b = tid >> 3, hid = tid & 7;
    float ssm = 0.0f;
    for (int jj = 0; jj < 256; jj++)
        ssm += hbuf[jj * 33 + b] * wbuf[hid * 256 + jj];
    atomicAdd(&acc[b * 8 + hid], ssm);
}

__global__ void k4_final(const float* __restrict__ acc, const float* __restrict__ b1,
                         const float* __restrict__ bn2g, const float* __restrict__ bn2b,
                         const float* __restrict__ W2, const float* __restrict__ b2,
                         float* __restrict__ out) {
    __shared__ float gl[256];
    __shared__ float m2[8], i2[8];
    int tid = threadIdx.x;
    int b = tid >> 3, hid = tid & 7;
    float x = acc[tid] + b1[hid];
    float ge = 0.5f * x * (1.0f + erff(x * 0.7071067811865476f));
    gl[tid] = ge;
    __syncthreads();
    if (tid < 8) {
        float s1 = 0.0f, s2 = 0.0f;
        for (int bb = 0; bb < 32; bb++) {
            float v = gl[bb * 8 + tid];
            s1 += v; s2 += v * v;
        }
        float mm = s1 * (1.0f / 32.0f);
        m2[tid] = mm;
        i2[tid] = rsqrtf(s2 * (1.0f / 32.0f) - mm * mm + 1e-5f);
    }
    __syncthreads();
    float h2 = (ge - m2[hid]) * i2[hid] * bn2g[hid] + bn2b[hid];
    gl[tid] = h2;
    __syncthreads();
    if (tid < 64) {
        int bo = tid >> 1, o = tid & 1;
        float ssm = b2[o];
        for (int hh = 0; hh < 8; hh++) ssm += gl[bo * 8 + hh] * W2[o * 8 + hh];
        out[bo * 2 + o] = ssm;
    }
}

// ---------------------------------------------------------------------------
extern "C" void kernel_launch(void* const* d_in, const int* in_sizes, int n_in,
                              void* d_out, int out_size, void* d_ws, size_t ws_size,
                              hipStream_t stream) {
    const float* X     = (const float*)d_in[0];
    const float* foi   = (const float*)d_in[1];
    const float* fwhm  = (const float*)d_in[2];
    const float* shrink= (const float*)d_in[3];
    const float* brn_w = (const float*)d_in[4];
    const float* bn1_g = (const float*)d_in[5];
    const float* bn1_b = (const float*)d_in[6];
    const float* W1    = (const float*)d_in[7];
    const float* b1    = (const float*)d_in[8];
    const float* bn2_g = (const float*)d_in[9];
    const float* bn2_b = (const float*)d_in[10];
    const float* W2    = (const float*)d_in[11];
    const float* b2    = (const float*)d_in[12];

    float* ws    = (float*)d_ws;
    _Float16* T16= (_Float16*)(ws + WS_T16);
    int*   iu    = (int*)(ws + WS_IU);
    int*   ju    = (int*)(ws + WS_JU);
    float* m_u   = ws + WS_MU;
    float* sc_u  = ws + WS_SC;
    float* acc   = ws + WS_ACC;
    float* cov   = ws + WS_COV;
    float* vec   = ws + WS_VEC;
    _Float16* Zbuf = (_Float16*)(ws + WS_Z);
    // dvec/dmu alias the (already consumed by then) Z region
    float* dvec  = (float*)(ws + WS_Z);
    float* dmuv  = dvec + 320 * 64;

    size_t zavail = (ws_size > (size_t)WS_Z * 4) ? ws_size - (size_t)WS_Z * 4 : 0;
    const int cand[6] = {2432, 1152, 768, 384, 256, 128};
    int Tchunk = 128;
    for (int i = 0; i < 6; i++) {
        if (81920ull * (size_t)cand[i] <= zavail) { Tchunk = cand[i]; break; }
    }

    hipMemsetAsync(cov, 0, 320 * 4096 * sizeof(float), stream);
    hipMemsetAsync(acc, 0, 256 * sizeof(float), stream);

    k0_build<<<1, 256, 0, stream>>>(foi, fwhm, T16, iu, ju);
    for (int t0 = 0; t0 < 2376; t0 += Tchunk) {
        int Tcur = min(Tchunk, 2376 - t0);
        int subs = (Tcur + 127) / 128;
        kconv<<<32 * subs, 256, 0, stream>>>(X, T16, Zbuf, t0, Tchunk, subs);
        kcov<<<320, 256, 0, stream>>>(Zbuf, cov, t0, Tcur, Tchunk);
    }
    keja6<<<320, 64, 0, stream>>>(cov, shrink, dvec, dmuv);
    kvec<<<320, 256, 0, stream>>>(cov, dvec, dmuv, iu, ju, vec);
    k3a_stats<<<9, 256, 0, stream>>>(vec, brn_w, m_u, sc_u);
    k3b_bn1mm<<<82, 256, 0, stream>>>(vec, m_u, sc_u, bn1_g, bn1_b, W1, acc);
    k4_final<<<1, 256, 0, stream>>>(acc, b1, bn2_g, bn2_b, W2, b2, (float*)d_out);
}

// Round 11
// 677.692 us; speedup vs baseline: 1.4253x; 1.4253x over previous
//
#include <hip/hip_runtime.h>
#include <math.h>

#define NSWEEP 9

// ws layout (float offsets)
#define WS_T16 0            // 32*128 f16 = 2048 floats
#define WS_IU  2048
#define WS_JU  4128
#define WS_MU  6208
#define WS_SC  8288
#define WS_ACC 10368
#define WS_COV 16384                     // 320*4096 floats
#define WS_VEC (16384 + 320*4096)        // 320*2080 floats
#define WS_Z   1994752                   // f16 Z buffer starts here (floats)

typedef _Float16 f16x8 __attribute__((ext_vector_type(8)));
typedef float f32x16 __attribute__((ext_vector_type(16)));
typedef float v2f __attribute__((ext_vector_type(2)));

union H8 { int4 i; f16x8 h; };
union HP { uint32_t u; _Float16 h[2]; };

__device__ inline f32x16 zero16() {
    f32x16 z;
#pragma unroll
    for (int r = 0; r < 16; r++) z[r] = 0.0f;
    return z;
}

__device__ __forceinline__ float bperm(int addr, float v) {
    return __int_as_float(__builtin_amdgcn_ds_bpermute(addr, __float_as_int(v)));
}

// ---------------------------------------------------------------------------
// K0: wavelet taps as fp16 matrix T16[32][128] + triu tables
// ---------------------------------------------------------------------------
__global__ void k0_build(const float* __restrict__ foi, const float* __restrict__ fwhm,
                         _Float16* __restrict__ T16,
                         int* __restrict__ iu, int* __restrict__ ju) {
    __shared__ float env[128];
    __shared__ float ssum;
    int tid = threadIdx.x;
    for (int u = tid; u < 2080; u += 256) {
        int i = 0, off = 0;
        while (off + (64 - i) <= u) { off += (64 - i); i++; }
        iu[u] = i;
        ju[u] = i + (u - off);
    }
    for (int idx = tid; idx < 32 * 128; idx += 256) T16[idx] = (_Float16)0.0f;
    __syncthreads();
    const float inv_sfreq = 1.0f / 250.0f;
    for (int f = 0; f < 10; f++) {
        float fhz = exp2f(foi[f]);
        float sig = exp2f(fwhm[f]) / (2.0f * sqrtf(2.0f * logf(2.0f)));
        if (tid < 128) {
            float e = 0.0f;
            if (tid < 125) {
                float t = ((float)tid - 62.0f) * inv_sfreq;
                float z = t / sig;
                e = expf(-0.5f * z * z);
            }
            env[tid] = e;
        }
        __syncthreads();
        if (tid == 0) {
            float s = 0.0f;
            for (int k = 0; k < 125; k++) s += env[k];
            ssum = s;
        }
        __syncthreads();
        if (tid < 125) {
            float e = env[tid] / ssum;
            float t = ((float)tid - 62.0f) * inv_sfreq;
            float ph = 6.283185307179586f * fhz * t;
            T16[f * 128 + tid] = (_Float16)(e * cosf(ph));
            T16[(10 + f) * 128 + tid] = (_Float16)(e * sinf(ph));
        }
        __syncthreads();
    }
}

// ---------------------------------------------------------------------------
// KCONV: fp16 MFMA conv (unchanged)
// ---------------------------------------------------------------------------
__global__ __launch_bounds__(256) void kconv(const float* __restrict__ X,
                                             const _Float16* __restrict__ T16,
                                             _Float16* __restrict__ Zbuf,
                                             int t0chunk, int Tpad, int subs) {
    __shared__ __align__(16) uint32_t P[64 * 256];
    int tid = threadIdx.x;
    int b = blockIdx.x / subs;
    int sub = blockIdx.x - b * subs;
    int tbase = t0chunk + sub * 128;
    const float* Xb = X + b * (64 * 2500);
    bool fastblk = (tbase + 256 < 2500);
    for (int task = tid; task < 64 * 64; task += 256) {
        int c = task >> 6, grp = task & 63;
        int t = tbase + grp * 4;
        const float* src = Xb + c * 2500 + t;
        float x0, x1, x2, x3, x4;
        if (fastblk) {
            float4 v = *(const float4*)src;
            x0 = v.x; x1 = v.y; x2 = v.z; x3 = v.w; x4 = src[4];
        } else {
            x0 = (t + 0 < 2500) ? src[0] : 0.0f;
            x1 = (t + 1 < 2500) ? src[1] : 0.0f;
            x2 = (t + 2 < 2500) ? src[2] : 0.0f;
            x3 = (t + 3 < 2500) ? src[3] : 0.0f;
            x4 = (t + 4 < 2500) ? src[4] : 0.0f;
        }
        HP p0, p1, p2, p3;
        p0.h[0] = (_Float16)x0; p0.h[1] = (_Float16)x1;
        p1.h[0] = (_Float16)x1; p1.h[1] = (_Float16)x2;
        p2.h[0] = (_Float16)x2; p2.h[1] = (_Float16)x3;
        p3.h[0] = (_Float16)x3; p3.h[1] = (_Float16)x4;
        uint4 up; up.x = p0.u; up.y = p1.u; up.z = p2.u; up.w = p3.u;
        *(uint4*)&P[c * 256 + grp * 4] = up;
    }
    __syncthreads();
    int lane = tid & 63;
    int w = tid >> 6;
    int n = lane & 31, g = lane >> 5;
    H8 a[8];
#pragma unroll
    for (int ks = 0; ks < 8; ks++)
        a[ks].i = *(const int4*)(T16 + n * 128 + ks * 16 + g * 8);
    int tw = w * 32;
    int colg = tbase + tw + n;
    bool colok = (colg < 2376);
    int tloc = sub * 128 + tw + n;
    int zb0 = b * 1280;
    for (int c = 0; c < 64; c++) {
        f32x16 acc = zero16();
        const uint32_t* Pc = &P[c * 256 + tw + n + 8 * g];
#pragma unroll
        for (int ks = 0; ks < 8; ks++) {
            H8 bv;
            bv.i.x = (int)Pc[16 * ks + 0];
            bv.i.y = (int)Pc[16 * ks + 2];
            bv.i.z = (int)Pc[16 * ks + 4];
            bv.i.w = (int)Pc[16 * ks + 6];
            acc = __builtin_amdgcn_mfma_f32_32x32x16_f16(a[ks].h, bv.h, acc, 0, 0, 0);
        }
        if (colok) {
            int zb = zb0 + c;
#pragma unroll
            for (int r = 0; r < 16; r++) {
                int row = (r & 3) + 8 * (r >> 2) + 4 * g;
                if (row < 20)
                    Zbuf[(zb + row * 64) * Tpad + tloc] = (_Float16)acc[r];
            }
        }
    }
}

// ---------------------------------------------------------------------------
// KCOV: per (b,f) covariance via MFMA (unchanged)
// ---------------------------------------------------------------------------
__global__ __launch_bounds__(256) void kcov(const _Float16* __restrict__ Zbuf,
                                            float* __restrict__ cov,
                                            int t0chunk, int Tcur, int Tpad) {
    __shared__ __align__(16) _Float16 Zs[2][64 * 100];
    int tid = threadIdx.x;
    int lane = tid & 63, w = tid >> 6;
    int n = lane & 31, g = lane >> 5;
    int bf = blockIdx.x;
    int b = bf / 10, f = bf - b * 10;
    const _Float16* Zr = Zbuf + (size_t)((b * 20 + f) * 64) * Tpad;
    const _Float16* Zi = Zbuf + (size_t)((b * 20 + 10 + f) * 64) * Tpad;
    int ti = w >> 1, tj = w & 1;
    f32x16 acc = zero16();
    int limit = min(Tcur, 2376 - t0chunk);
    int nsub = (limit + 95) / 96;
    for (int sc = 0; sc < nsub; sc++) {
        int tl0 = sc * 96;
        __syncthreads();
        for (int task = tid; task < 1536; task += 256) {
            int arr = task / 768;
            int rem = task - arr * 768;
            int c = rem / 12;
            int o = (rem - c * 12) * 8;
            int tg = tl0 + o;
            const _Float16* src = (arr ? Zi : Zr) + c * Tpad + tg;
            H8 v;
            if (tg + 8 <= limit) {
                v.i = *(const int4*)src;
            } else {
#pragma unroll
                for (int j2 = 0; j2 < 8; j2++)
                    v.h[j2] = (tg + j2 < limit) ? src[j2] : (_Float16)0.0f;
            }
            *(int2*)&Zs[arr][c * 100 + o] = make_int2(v.i.x, v.i.y);
            *(int2*)&Zs[arr][c * 100 + o + 4] = make_int2(v.i.z, v.i.w);
        }
        __syncthreads();
        int ra = (32 * ti + n) * 100 + g * 8;
        int rb = (32 * tj + n) * 100 + g * 8;
#pragma unroll
        for (int arr = 0; arr < 2; arr++) {
#pragma unroll
            for (int ks = 0; ks < 6; ks++) {
                const _Float16* pa = &Zs[arr][ra + ks * 16];
                const _Float16* pb = &Zs[arr][rb + ks * 16];
                int2 a0 = *(const int2*)pa;
                int2 a1 = *(const int2*)(pa + 4);
                int2 b0 = *(const int2*)pb;
                int2 b1 = *(const int2*)(pb + 4);
                H8 av, bv;
                av.i = make_int4(a0.x, a0.y, a1.x, a1.y);
                bv.i = make_int4(b0.x, b0.y, b1.x, b1.y);
                acc = __builtin_amdgcn_mfma_f32_32x32x16_f16(av.h, bv.h, acc, 0, 0, 0);
            }
        }
    }
    float* covbf = cov + bf * 4096;
    int col = 32 * tj + n;
#pragma unroll
    for (int r = 0; r < 16; r++) {
        int row = 32 * ti + (r & 3) + 8 * (r >> 2) + 4 * g;
        covbf[row * 64 + col] += acc[r];
    }
}

// ---------------------------------------------------------------------------
// KEJA7: one-sided Jacobi, one wave per matrix. Based on keja5 (r9, 376 us,
// best) — r10's LDS mirror is structurally bank-conflicted (column base
// s*64 ≡ 0 mod 32 banks -> 8-way pigeonhole) and reverted.
// Two changes vs keja5:
//  1. packed fp32 (float2 ext-vectors -> v_pk_fma_f32, full-rate on CDNA):
//     dot 64->32 instr, update 128->64 instr.
//  2. prefetch depth 2 (triple-buffered q[3][4] float2 chunks): fetch c+2
//     during chunk c, putting ~140 cyc between bpermute issue and use
//     (vs ~72 at depth 1, ~120 cyc latency -> was ~50 cyc stall/chunk).
// Refetch in update pass is wave-synchronous-correct (chunk c+2 fetched at
// iteration c, updated at c+2; registers are private, bpermute reads current
// values in lockstep). ~103 live floats -> all-arch VGPR, no AGPR shuttle.
// ---------------------------------------------------------------------------
__global__ __launch_bounds__(64, 1) void keja7(float* __restrict__ cov,
                                               const float* __restrict__ shrink,
                                               float* __restrict__ dvec,
                                               float* __restrict__ dmu) {
    int s = threadIdx.x;            // lane = column
    int bf = blockIdx.x;
    float* C = cov + bf * 4096;
    v2f w2[32];
#pragma unroll
    for (int r = 0; r < 32; r++) {
        w2[r].x = C[(2 * r) * 64 + s];
        w2[r].y = C[(2 * r + 1) * 64 + s];
    }
    // trace -> mu
    float ts = C[s * 65];
#pragma unroll
    for (int m = 1; m < 64; m <<= 1) ts += __shfl_xor(ts, m, 64);
    float mu = ts * (1.0f / (64.0f * 2376.0f));
    float alpha = 1.0f / (1.0f + expf(-shrink[0]));
    float scl = (1.0f - alpha) / (2376.0f * fmaxf(mu, 1e-30f));
    v2f scl2 = {scl, scl};
#pragma unroll
    for (int r = 0; r < 32; r++) {
        v2f v = w2[r] * scl2;
        if (2 * r == s) v.x += alpha;
        if (2 * r + 1 == s) v.y += alpha;
        w2[r] = v;
    }
#define FETCH(K, B)                                                             \
    {                                                                           \
        q[B][0].x = bperm(addr, w2[(K) * 4 + 0].x);                             \
        q[B][0].y = bperm(addr, w2[(K) * 4 + 0].y);                             \
        q[B][1].x = bperm(addr, w2[(K) * 4 + 1].x);                             \
        q[B][1].y = bperm(addr, w2[(K) * 4 + 1].y);                             \
        q[B][2].x = bperm(addr, w2[(K) * 4 + 2].x);                             \
        q[B][2].y = bperm(addr, w2[(K) * 4 + 2].y);                             \
        q[B][3].x = bperm(addr, w2[(K) * 4 + 3].x);                             \
        q[B][3].y = bperm(addr, w2[(K) * 4 + 3].y);                             \
    }
    float nrm = 0.0f;
    for (int sweep = 0; sweep < NSWEEP; sweep++) {
        // fresh column norm at sweep start (kills carried-norm drift)
        {
            v2f n0 = {0.0f, 0.0f}, n1 = {0.0f, 0.0f};
#pragma unroll
            for (int r = 0; r < 32; r += 2) {
                n0 = w2[r] * w2[r] + n0;
                n1 = w2[r + 1] * w2[r + 1] + n1;
            }
            v2f nt = n0 + n1;
            nrm = nt.x + nt.y;
        }
        for (int m = 1; m < 64; m++) {
            int addr = (s ^ m) << 2;
            float pn = bperm(addr, nrm);     // lands during the dot
            v2f q[3][4];
            // ---- pass 1: dot, depth-2 chunked prefetch ----
            FETCH(0, 0)
            FETCH(1, 1)
            v2f dd0 = {0.0f, 0.0f}, dd1 = {0.0f, 0.0f};
#pragma unroll
            for (int c = 0; c < 8; c++) {
                if (c < 6) FETCH(c + 2, (c + 2) % 3)
                const int cb = c % 3;
                dd0 = w2[c * 4 + 0] * q[cb][0] + dd0;
                dd1 = w2[c * 4 + 1] * q[cb][1] + dd1;
                dd0 = w2[c * 4 + 2] * q[cb][2] + dd0;
                dd1 = w2[c * 4 + 3] * q[cb][3] + dd1;
            }
            v2f ddt = dd0 + dd1;
            float dpq = ddt.x + ddt.y;
            int h = 31 - __builtin_clz((unsigned)m);
            bool top = (((s >> h) & 1) == 0);
            float dpp = top ? nrm : pn;
            float dqq = top ? pn : nrm;
            bool rot = (dpq * dpq > 1e-13f * dpp * dqq);
            // fast rotation: v_rcp / v_sqrt / v_rsq approx (rot gate kills NaN)
            float tau = (dqq - dpp) * 0.5f * __builtin_amdgcn_rcpf(dpq);
            float tt = __builtin_amdgcn_rcpf(fabsf(tau) +
                        __builtin_amdgcn_sqrtf(fmaf(tau, tau, 1.0f)));
            tt = (tau < 0.0f) ? -tt : tt;
            if (!rot) tt = 0.0f;
            float cc = __builtin_amdgcn_rsqf(fmaf(tt, tt, 1.0f));
            float ssn = tt * cc;
            float sg = top ? -ssn : ssn;
            v2f cc2 = {cc, cc};
            v2f sg2 = {sg, sg};
            // ---- pass 2: update, depth-2 chunked refetch (values identical
            // to pass 1; chunk c+2 fetched at iter c, updated at iter c+2) ----
            FETCH(0, 0)
            FETCH(1, 1)
#pragma unroll
            for (int c = 0; c < 8; c++) {
                if (c < 6) FETCH(c + 2, (c + 2) % 3)
                const int cb = c % 3;
                w2[c * 4 + 0] = cc2 * w2[c * 4 + 0] + sg2 * q[cb][0];
                w2[c * 4 + 1] = cc2 * w2[c * 4 + 1] + sg2 * q[cb][1];
                w2[c * 4 + 2] = cc2 * w2[c * 4 + 2] + sg2 * q[cb][2];
                w2[c * 4 + 3] = cc2 * w2[c * 4 + 3] + sg2 * q[cb][3];
            }
            nrm = fmaf(top ? -tt : tt, dpq, nrm);   // exact norm update
        }
    }
#undef FETCH
    // final exact column norm + output: column s = lambda_s * v_s
    v2f n0 = {0.0f, 0.0f}, n1 = {0.0f, 0.0f};
#pragma unroll
    for (int r = 0; r < 32; r += 2) {
        n0 = w2[r] * w2[r] + n0;
        n1 = w2[r + 1] * w2[r + 1] + n1;
    }
    v2f nt = n0 + n1;
    float nf = nt.x + nt.y;
#pragma unroll
    for (int r = 0; r < 32; r++) {
        C[(2 * r) * 64 + s] = w2[r].x;
        C[(2 * r + 1) * 64 + s] = w2[r].y;
    }
    dvec[bf * 64 + s] = 0.5f * logf(nf) / nf;   // log(lambda)/lambda^2
    if (s == 0) dmu[bf] = logf(fmaxf(mu, 1e-30f));
}

// ---------------------------------------------------------------------------
// KVEC: logC = sum_s d_s w_s w_s^T ; triu vectorize with sqrt2 / +logmu diag
// ---------------------------------------------------------------------------
__global__ __launch_bounds__(256) void kvec(const float* __restrict__ W,
                                            const float* __restrict__ dvec,
                                            const float* __restrict__ dmu,
                                            const int* __restrict__ iu,
                                            const int* __restrict__ ju,
                                            float* __restrict__ vec) {
    __shared__ float WL[64 * 68];
    __shared__ float WD[64 * 68];
    __shared__ float ds[64];
    int tid = threadIdx.x;
    int bf = blockIdx.x;
    const float* Wb = W + bf * 4096;
    if (tid < 64) ds[tid] = dvec[bf * 64 + tid];
    __syncthreads();
    for (int idx = tid; idx < 4096; idx += 256) {
        int i = idx >> 6, c = idx & 63;
        float v = Wb[idx];
        WL[i * 68 + c] = v;
        WD[i * 68 + c] = v * ds[c];
    }
    __syncthreads();
    float logmu = dmu[bf];
    float* out = vec + bf * 2080;
    for (int u = tid; u < 2080; u += 256) {
        int i = iu[u], j = ju[u];
        const float* a = &WD[i * 68];
        const float* b = &WL[j * 68];
        float s0 = 0, s1 = 0, s2 = 0, s3 = 0;
#pragma unroll
        for (int k = 0; k < 64; k += 16) {
            float4 a0 = *(const float4*)(a + k);
            float4 b0 = *(const float4*)(b + k);
            float4 a1 = *(const float4*)(a + k + 4);
            float4 b1 = *(const float4*)(b + k + 4);
            float4 a2 = *(const float4*)(a + k + 8);
            float4 b2 = *(const float4*)(b + k + 8);
            float4 a3 = *(const float4*)(a + k + 12);
            float4 b3 = *(const float4*)(b + k + 12);
            s0 = fmaf(a0.x, b0.x, fmaf(a0.y, b0.y, fmaf(a0.z, b0.z, fmaf(a0.w, b0.w, s0))));
            s1 = fmaf(a1.x, b1.x, fmaf(a1.y, b1.y, fmaf(a1.z, b1.z, fmaf(a1.w, b1.w, s1))));
            s2 = fmaf(a2.x, b2.x, fmaf(a2.y, b2.y, fmaf(a2.z, b2.z, fmaf(a2.w, b2.w, s2))));
            s3 = fmaf(a3.x, b3.x, fmaf(a3.y, b3.y, fmaf(a3.z, b3.z, fmaf(a3.w, b3.w, s3))));
        }
        float ssm = (s0 + s1) + (s2 + s3);
        if (i == j) ssm += logmu;
        else ssm *= 1.4142135623730951f;
        out[u] = ssm;
    }
}

// ---------------------------------------------------------------------------
__global__ void k3a_stats(const float* __restrict__ vec, const float* __restrict__ brn_w,
                          float* __restrict__ m_u, float* __restrict__ sc_u) {
    int u = blockIdx.x * 256 + threadIdx.x;
    if (u >= 2080) return;
    float s1 = 0.0f, s2 = 0.0f;
    for (int bfi = 0; bfi < 320; bfi++) {
        float x = vec[bfi * 2080 + u];
        s1 += x; s2 += x * x;
    }
    float m = s1 * (1.0f / 320.0f);
    float v = s2 * (1.0f / 320.0f) - m * m;
    m_u[u] = m;
    sc_u[u] = brn_w[u] * rsqrtf(v + 1e-5f);
}

__global__ __launch_bounds__(256) void k3b_bn1mm(const float* __restrict__ vec,
                                                 const float* __restrict__ m_u,
                                                 const float* __restrict__ sc_u,
                                                 const float* __restrict__ g1,
                                                 const float* __restrict__ bb1,
                                                 const float* __restrict__ W1,
                                                 float* __restrict__ acc) {
    __shared__ float hbuf[256 * 33];
    __shared__ float wbuf[8 * 256];
    int tid = threadIdx.x;
    int j = blockIdx.x * 256 + tid;
    bool act = (j < 20800);
    int f = act ? (j / 2080) : 0;
    int u = act ? (j % 2080) : 0;
    float mm = act ? m_u[u] : 0.0f;
    float sc = act ? sc_u[u] : 0.0f;
    float xv[32];
    float s1 = 0.0f, s2 = 0.0f;
    for (int b = 0; b < 32; b++) {
        float x = act ? ((vec[(b * 10 + f) * 2080 + u] - mm) * sc) : 0.0f;
        xv[b] = x;
        s1 += x; s2 += x * x;
    }
    float m1 = s1 * (1.0f / 32.0f);
    float inv1 = rsqrtf(s2 * (1.0f / 32.0f) - m1 * m1 + 1e-5f);
    float gg = act ? g1[j] : 0.0f;
    float bb = act ? bb1[j] : 0.0f;
    for (int b = 0; b < 32; b++)
        hbuf[tid * 33 + b] = (xv[b] - m1) * inv1 * gg + bb;
    for (int hid = 0; hid < 8; hid++)
        wbuf[hid * 256 + tid] = act ? W1[hid * 20800 + j] : 0.0f;
    __syncthreads();
    int b = tid >> 3, hid = tid & 7;
    float ssm = 0.0f;
    for (int jj = 0; jj < 256; jj++)
        ssm += hbuf[jj * 33 + b] * wbuf[hid * 256 + jj];
    atomicAdd(&acc[b * 8 + hid], ssm);
}

__global__ void k4_final(const float* __restrict__ acc, const float* __restrict__ b1,
                         const float* __restrict__ bn2g, const float* __restrict__ bn2b,
                         const float* __restrict__ W2, const float* __restrict__ b2,
                         float* __restrict__ out) {
    __shared__ float gl[256];
    __shared__ float m2[8], i2[8];
    int tid = threadIdx.x;
    int b = tid >> 3, hid = tid & 7;
    float x = acc[tid] + b1[hid];
    float ge = 0.5f * x * (1.0f + erff(x * 0.7071067811865476f));
    gl[tid] = ge;
    __syncthreads();
    if (tid < 8) {
        float s1 = 0.0f, s2 = 0.0f;
        for (int bb = 0; bb < 32; bb++) {
            float v = gl[bb * 8 + tid];
            s1 += v; s2 += v * v;
        }
        float mm = s1 * (1.0f / 32.0f);
        m2[tid] = mm;
        i2[tid] = rsqrtf(s2 * (1.0f / 32.0f) - mm * mm + 1e-5f);
    }
    __syncthreads();
    float h2 = (ge - m2[hid]) * i2[hid] * bn2g[hid] + bn2b[hid];
    gl[tid] = h2;
    __syncthreads();
    if (tid < 64) {
        int bo = tid >> 1, o = tid & 1;
        float ssm = b2[o];
        for (int hh = 0; hh < 8; hh++) ssm += gl[bo * 8 + hh] * W2[o * 8 + hh];
        out[bo * 2 + o] = ssm;
    }
}

// ---------------------------------------------------------------------------
extern "C" void kernel_launch(void* const* d_in, const int* in_sizes, int n_in,
                              void* d_out, int out_size, void* d_ws, size_t ws_size,
                              hipStream_t stream) {
    const float* X     = (const float*)d_in[0];
    const float* foi   = (const float*)d_in[1];
    const float* fwhm  = (const float*)d_in[2];
    const float* shrink= (const float*)d_in[3];
    const float* brn_w = (const float*)d_in[4];
    const float* bn1_g = (const float*)d_in[5];
    const float* bn1_b = (const float*)d_in[6];
    const float* W1    = (const float*)d_in[7];
    const float* b1    = (const float*)d_in[8];
    const float* bn2_g = (const float*)d_in[9];
    const float* bn2_b = (const float*)d_in[10];
    const float* W2    = (const float*)d_in[11];
    const float* b2    = (const float*)d_in[12];

    float* ws    = (float*)d_ws;
    _Float16* T16= (_Float16*)(ws + WS_T16);
    int*   iu    = (int*)(ws + WS_IU);
    int*   ju    = (int*)(ws + WS_JU);
    float* m_u   = ws + WS_MU;
    float* sc_u  = ws + WS_SC;
    float* acc   = ws + WS_ACC;
    float* cov   = ws + WS_COV;
    float* vec   = ws + WS_VEC;
    _Float16* Zbuf = (_Float16*)(ws + WS_Z);
    // dvec/dmu alias the (already consumed by then) Z region
    float* dvec  = (float*)(ws + WS_Z);
    float* dmuv  = dvec + 320 * 64;

    size_t zavail = (ws_size > (size_t)WS_Z * 4) ? ws_size - (size_t)WS_Z * 4 : 0;
    const int cand[6] = {2432, 1152, 768, 384, 256, 128};
    int Tchunk = 128;
    for (int i = 0; i < 6; i++) {
        if (81920ull * (size_t)cand[i] <= zavail) { Tchunk = cand[i]; break; }
    }

    hipMemsetAsync(cov, 0, 320 * 4096 * sizeof(float), stream);
    hipMemsetAsync(acc, 0, 256 * sizeof(float), stream);

    k0_build<<<1, 256, 0, stream>>>(foi, fwhm, T16, iu, ju);
    for (int t0 = 0; t0 < 2376; t0 += Tchunk) {
        int Tcur = min(Tchunk, 2376 - t0);
        int subs = (Tcur + 127) / 128;
        kconv<<<32 * subs, 256, 0, stream>>>(X, T16, Zbuf, t0, Tchunk, subs);
        kcov<<<320, 256, 0, stream>>>(Zbuf, cov, t0, Tcur, Tchunk);
    }
    keja7<<<320, 64, 0, stream>>>(cov, shrink, dvec, dmuv);
    kvec<<<320, 256, 0, stream>>>(cov, dvec, dmuv, iu, ju, vec);
    k3a_stats<<<9, 256, 0, stream>>>(vec, brn_w, m_u, sc_u);
    k3b_bn1mm<<<82, 256, 0, stream>>>(vec, m_u, sc_u, bn1_g, bn1_b, W1, acc);
    k4_final<<<1, 256, 0, stream>>>(acc, b1, bn2_g, bn2_b, W2, b2, (float*)d_out);
}